// Round 6
// baseline (294.167 us; speedup 1.0000x reference)
//
#include <hip/hip_runtime.h>
#include <hip/hip_fp16.h>
#include <math.h>

#define N_NODES 50000
#define N_EDGES 1600000
#define N_GRAPHS 512
#define HID 32
#define NEG_SLOPE 0.2f
#define SM_EPS 1e-16f
#define PAD 80          // max in-degree slots; dst~Poisson(32), P(deg>=80)*N ~ 5e-7
#define NSHARD 8        // = XCD count
#define SHARD_SZ 6250   // N_NODES / NSHARD
#define PART_CAP 208000 // per-shard partition capacity: 200k mean + ~19 sigma

// ---------------- kernel 1: partition edges into 8 dst-range shards ----------------
// Block-aggregated append: LDS rank per shard, 8 global atomics per block-chunk,
// ~256B contiguous runs per shard -> coalesced partition writes.
__global__ __launch_bounds__(256) void k_part(const int* __restrict__ ei,
                                              const float* __restrict__ ea,
                                              const float* __restrict__ W_edge,
                                              const float* __restrict__ att_edge,
                                              uint2* __restrict__ part,
                                              int* __restrict__ pcur) {
    __shared__ float sv[3];
    __shared__ int lcnt[NSHARD], lbase[NSHARD];
    int t = threadIdx.x;
    if (t < 3) {
        float v = 0.f;
        for (int j = 0; j < 32; ++j) v += W_edge[t * 32 + j] * att_edge[j];
        sv[t] = v;
    }
    __syncthreads();
    int stride = gridDim.x * blockDim.x;
    int iters = (N_EDGES + stride - 1) / stride;
    for (int it = 0; it < iters; ++it) {
        int e = it * stride + blockIdx.x * blockDim.x + t;
        bool valid = e < N_EDGES;
        if (t < NSHARD) lcnt[t] = 0;
        __syncthreads();
        int shard = 0, rank = 0;
        uint2 r;
        if (valid) {
            int s = ei[e];
            int d = ei[N_EDGES + e];
            float aev = ea[e * 3 + 0] * sv[0] + ea[e * 3 + 1] * sv[1] + ea[e * 3 + 2] * sv[2];
            shard = (d * NSHARD) / N_NODES;
            r = make_uint2((unsigned)d | ((unsigned)s << 16), __float_as_uint(aev));
            rank = atomicAdd(&lcnt[shard], 1);
        }
        __syncthreads();
        if (t < NSHARD) lbase[t] = atomicAdd(pcur + t, lcnt[t]);
        __syncthreads();
        if (valid) {
            int pos = lbase[shard] + rank;
            if (pos < PART_CAP) part[(size_t)shard * PART_CAP + pos] = r;
        }
    }
}

// ---------------- kernel 2: XCD-sharded bucket placement (reads own partition only) ----------------
__global__ __launch_bounds__(256) void k_place2(const uint2* __restrict__ part,
                                                const int* __restrict__ pcur,
                                                int* __restrict__ cursor,
                                                unsigned* __restrict__ bucket) {
    int shard = blockIdx.x & (NSHARD - 1);
    int cnt = pcur[shard];
    const uint2* p = part + (size_t)shard * PART_CAP;
    int bid = blockIdx.x >> 3;
    int nb = gridDim.x >> 3;
    int stride = nb * blockDim.x;
    for (int i = bid * blockDim.x + threadIdx.x; i < cnt; i += stride) {
        unsigned long long rv = __builtin_nontemporal_load((const unsigned long long*)(p + i));
        unsigned lo = (unsigned)rv;
        unsigned hi = (unsigned)(rv >> 32);
        int d = lo & 0xFFFF;
        unsigned s = lo >> 16;
        unsigned short hb = __half_as_ushort(__float2half_rn(__uint_as_float(hi)));
        int pos = atomicAdd(cursor + d, 1);
        if (pos < PAD) bucket[(size_t)d * PAD + pos] = s | ((unsigned)hb << 16);
    }
}

// ---------------- kernel 3: node transform h = x@W, a_src, a_dst ----------------
__global__ void k_node(const float* __restrict__ x, const float* __restrict__ W,
                       const float* __restrict__ att_src, const float* __restrict__ att_dst,
                       float* __restrict__ h, float* __restrict__ a_src, float* __restrict__ a_dst) {
    __shared__ float sW[12 * 32];
    __shared__ float sas[32], sad[32];
    int t = threadIdx.x;
    for (int i = t; i < 12 * 32; i += blockDim.x) sW[i] = W[i];
    if (t < 32) { sas[t] = att_src[t]; sad[t] = att_dst[t]; }
    __syncthreads();
    int n = blockIdx.x * blockDim.x + t;
    if (n >= N_NODES) return;

    float xv[12];
#pragma unroll
    for (int j = 0; j < 12; ++j) xv[j] = x[n * 12 + j];

    float as = 0.f, ad = 0.f;
#pragma unroll
    for (int k = 0; k < 32; ++k) {
        float acc = 0.f;
#pragma unroll
        for (int j = 0; j < 12; ++j) acc += xv[j] * sW[j * 32 + k];
        h[(size_t)n * 32 + k] = acc;
        as += acc * sas[k];
        ad += acc * sad[k];
    }
    a_src[n] = as;
    a_dst[n] = ad;
}

// ---------------- kernel 4: graph boundary offsets (batch is sorted) ----------------
__global__ void k_goff(const int* __restrict__ batch, int* __restrict__ go) {
    int g = blockIdx.x * blockDim.x + threadIdx.x;
    if (g > N_GRAPHS) return;
    if (g == N_GRAPHS) { go[g] = N_NODES; return; }
    int lo = 0, hi = N_NODES;
    while (lo < hi) {
        int mid = (lo + hi) >> 1;
        if (batch[mid] < g) lo = mid + 1; else hi = mid;
    }
    go[g] = lo;
}

// ---------------- kernel 5: wave-per-node gather; lane = (es 0..15, cg 0..3 x 8ch) ----------------
__global__ __launch_bounds__(256) void k_gather(const int* __restrict__ cursor,
                                                const unsigned* __restrict__ bucket,
                                                const float* __restrict__ h,
                                                const float* __restrict__ a_src,
                                                const float* __restrict__ a_dst,
                                                const float* __restrict__ bias,
                                                const float* __restrict__ W_gate,
                                                const float* __restrict__ b_gate,
                                                float* __restrict__ oacc,
                                                float* __restrict__ ge) {
    int n = blockIdx.x * (blockDim.x >> 6) + (threadIdx.x >> 6);
    if (n >= N_NODES) return;
    int l = threadIdx.x & 63;
    int es = l >> 2;        // edge subgroup 0..15
    int cg = l & 3;         // channel group 0..3 (8 floats: cg*8 .. cg*8+7)

    int deg_full = cursor[n];
    int degc = deg_full < PAD ? deg_full : PAD;
    float adst_n = a_dst[n];
    const unsigned* row = bucket + (size_t)n * PAD;

    float c0 = 0.f, c1 = 0.f, c2 = 0.f, c3 = 0.f, c4 = 0.f, c5 = 0.f, c6 = 0.f, c7 = 0.f;
    float wsum = 0.f, aevsum = 0.f;
    int j = es;
    for (; j + 16 < degc; j += 32) {
        // two entries, fully independent load chains
        unsigned p0 = row[j], p1 = row[j + 16];
        int s0 = p0 & 0xFFFF, s1 = p1 & 0xFFFF;
        float aev0 = __half2float(__ushort_as_half((unsigned short)(p0 >> 16)));
        float aev1 = __half2float(__ushort_as_half((unsigned short)(p1 >> 16)));
        float as0 = a_src[s0], as1 = a_src[s1];
        const float4 ha0 = *(const float4*)(h + (size_t)s0 * 32 + cg * 8);
        const float4 hb0 = *(const float4*)(h + (size_t)s0 * 32 + cg * 8 + 4);
        const float4 ha1 = *(const float4*)(h + (size_t)s1 * 32 + cg * 8);
        const float4 hb1 = *(const float4*)(h + (size_t)s1 * 32 + cg * 8 + 4);
        float a0 = as0 + adst_n + aev0; a0 = a0 > 0.f ? a0 : NEG_SLOPE * a0;
        float a1 = as1 + adst_n + aev1; a1 = a1 > 0.f ? a1 : NEG_SLOPE * a1;
        float w0 = __expf(a0), w1 = __expf(a1);
        wsum += w0 + w1; aevsum += aev0 + aev1;
        c0 += w0 * ha0.x + w1 * ha1.x;  c1 += w0 * ha0.y + w1 * ha1.y;
        c2 += w0 * ha0.z + w1 * ha1.z;  c3 += w0 * ha0.w + w1 * ha1.w;
        c4 += w0 * hb0.x + w1 * hb1.x;  c5 += w0 * hb0.y + w1 * hb1.y;
        c6 += w0 * hb0.z + w1 * hb1.z;  c7 += w0 * hb0.w + w1 * hb1.w;
    }
    if (j < degc) {
        unsigned p0 = row[j];
        int s0 = p0 & 0xFFFF;
        float aev0 = __half2float(__ushort_as_half((unsigned short)(p0 >> 16)));
        float a0 = a_src[s0] + adst_n + aev0; a0 = a0 > 0.f ? a0 : NEG_SLOPE * a0;
        float w0 = __expf(a0);
        const float4 ha0 = *(const float4*)(h + (size_t)s0 * 32 + cg * 8);
        const float4 hb0 = *(const float4*)(h + (size_t)s0 * 32 + cg * 8 + 4);
        wsum += w0; aevsum += aev0;
        c0 += w0 * ha0.x; c1 += w0 * ha0.y; c2 += w0 * ha0.z; c3 += w0 * ha0.w;
        c4 += w0 * hb0.x; c5 += w0 * hb0.y; c6 += w0 * hb0.z; c7 += w0 * hb0.w;
    }

    // reduce over edge-subgroups (lanes sharing cg): xor masks 4,8,16,32
#pragma unroll
    for (int m = 4; m <= 32; m <<= 1) {
        c0 += __shfl_xor(c0, m); c1 += __shfl_xor(c1, m);
        c2 += __shfl_xor(c2, m); c3 += __shfl_xor(c3, m);
        c4 += __shfl_xor(c4, m); c5 += __shfl_xor(c5, m);
        c6 += __shfl_xor(c6, m); c7 += __shfl_xor(c7, m);
        wsum += __shfl_xor(wsum, m); aevsum += __shfl_xor(aevsum, m);
    }

    // self-loop: aev_loop = mean incoming aev
    float dgm = deg_full > 1 ? (float)deg_full : 1.f;
    float al = a_src[n] + adst_n + aevsum / dgm;
    al = al > 0.f ? al : NEG_SLOPE * al;
    float el = __expf(al);
    float zi = 1.f / (wsum + el + SM_EPS);

    if (es == 0) {          // lanes 0..3, 8 channels each
        const float4 hna = *(const float4*)(h + (size_t)n * 32 + cg * 8);
        const float4 hnb = *(const float4*)(h + (size_t)n * 32 + cg * 8 + 4);
        const float4 bva = *(const float4*)(bias + cg * 8);
        const float4 bvb = *(const float4*)(bias + cg * 8 + 4);
        float4 va, vb;
        va.x = (c0 + el * hna.x) * zi + bva.x;
        va.y = (c1 + el * hna.y) * zi + bva.y;
        va.z = (c2 + el * hna.z) * zi + bva.z;
        va.w = (c3 + el * hna.w) * zi + bva.w;
        vb.x = (c4 + el * hnb.x) * zi + bvb.x;
        vb.y = (c5 + el * hnb.y) * zi + bvb.y;
        vb.z = (c6 + el * hnb.z) * zi + bvb.z;
        vb.w = (c7 + el * hnb.w) * zi + bvb.w;
        va.x = va.x > 0.f ? va.x : 0.f;  va.y = va.y > 0.f ? va.y : 0.f;
        va.z = va.z > 0.f ? va.z : 0.f;  va.w = va.w > 0.f ? va.w : 0.f;
        vb.x = vb.x > 0.f ? vb.x : 0.f;  vb.y = vb.y > 0.f ? vb.y : 0.f;
        vb.z = vb.z > 0.f ? vb.z : 0.f;  vb.w = vb.w > 0.f ? vb.w : 0.f;
        *(float4*)(oacc + (size_t)n * 32 + cg * 8) = va;
        *(float4*)(oacc + (size_t)n * 32 + cg * 8 + 4) = vb;
        const float4 wga = *(const float4*)(W_gate + cg * 8);
        const float4 wgb = *(const float4*)(W_gate + cg * 8 + 4);
        float g = va.x * wga.x + va.y * wga.y + va.z * wga.z + va.w * wga.w
                + vb.x * wgb.x + vb.y * wgb.y + vb.z * wgb.z + vb.w * wgb.w;
        g += __shfl_xor(g, 1);
        g += __shfl_xor(g, 2);
        if (cg == 0) {
            g += b_gate[0];
            ge[n] = __expf(g);
        }
    }
}

// ---------------- kernel 6: per-graph pooling + output head ----------------
__global__ __launch_bounds__(256) void k_pool_out(const float* __restrict__ oacc,
                                                  const float* __restrict__ ge,
                                                  const int* __restrict__ go,
                                                  const float* __restrict__ W_out,
                                                  const float* __restrict__ b_out,
                                                  float* __restrict__ out) {
    int g = blockIdx.x;
    int beg = go[g], end = go[g + 1];
    int t = threadIdx.x;
    __shared__ float swz[4];
    __shared__ float part[8][32];
    __shared__ float sgz;

    float s = 0.f;
    for (int n = beg + t; n < end; n += 256) s += ge[n];
#pragma unroll
    for (int ofs = 32; ofs > 0; ofs >>= 1) s += __shfl_down(s, ofs);
    if ((t & 63) == 0) swz[t >> 6] = s;
    __syncthreads();
    if (t == 0) sgz = swz[0] + swz[1] + swz[2] + swz[3];
    __syncthreads();
    float gz = sgz;

    int c = t & 31, ng = t >> 5;
    float acc = 0.f;
    for (int n = beg + ng; n < end; n += 8)
        acc += oacc[(size_t)n * 32 + c] * ge[n];
    part[ng][c] = acc;
    __syncthreads();
    if (t < 32) {
        float p = 0.f;
#pragma unroll
        for (int i = 0; i < 8; ++i) p += part[i][t];
        p /= (gz + SM_EPS);
        float o = p * W_out[t];
#pragma unroll
        for (int ofs = 16; ofs > 0; ofs >>= 1) o += __shfl_down(o, ofs);
        if (t == 0) out[g] = 1.f / (1.f + __expf(-(o + b_out[0])));
    }
}

extern "C" void kernel_launch(void* const* d_in, const int* in_sizes, int n_in,
                              void* d_out, int out_size, void* d_ws, size_t ws_size,
                              hipStream_t stream) {
    const float* x        = (const float*)d_in[0];
    const int*   ei       = (const int*)  d_in[1];
    const float* ea       = (const float*)d_in[2];
    const int*   batch    = (const int*)  d_in[3];
    const float* W        = (const float*)d_in[4];
    const float* att_src  = (const float*)d_in[5];
    const float* att_dst  = (const float*)d_in[6];
    const float* W_edge   = (const float*)d_in[7];
    const float* att_edge = (const float*)d_in[8];
    const float* bias     = (const float*)d_in[9];
    const float* W_gate   = (const float*)d_in[10];
    const float* b_gate   = (const float*)d_in[11];
    const float* W_out    = (const float*)d_in[12];
    const float* b_out    = (const float*)d_in[13];
    float* out = (float*)d_out;

    // workspace layout (part and oacc overlap: part dead after k_place2, oacc born in k_gather)
    char* wsb = (char*)d_ws;
    uint2*    part_  = (uint2*)wsb;                              // 8*PART_CAP uint2 = 13.3 MB
    float*    oacc   = (float*)wsb;                              // 32N floats = 6.4 MB (union)
    char*     p1     = wsb + (size_t)NSHARD * PART_CAP * sizeof(uint2);
    float*    h      = (float*)p1;                               // 32N
    unsigned* bucket = (unsigned*)(h + (size_t)32 * N_NODES);    // N*PAD uint = 16 MB
    float*    a_src  = (float*)(bucket + (size_t)N_NODES * PAD); // N
    float*    a_dst  = a_src + N_NODES;                          // N
    float*    ge     = a_dst + N_NODES;                          // N
    int*      go     = (int*)(ge + N_NODES);                     // G+1
    // ---- zeroed region ----
    int*      cursor = go + N_GRAPHS + 1;                        // N
    int*      pcur   = cursor + N_NODES;                         // NSHARD

    hipMemsetAsync(cursor, 0, (size_t)(N_NODES + NSHARD) * sizeof(int), stream);

    const int B = 256;
    // 625 blocks x 256 = 160000 threads -> exactly 10 full iterations over 1.6M edges
    k_part<<<625, B, 0, stream>>>(ei, ea, W_edge, att_edge, part_, pcur);
    k_node<<<(N_NODES + B - 1) / B, B, 0, stream>>>(x, W, att_src, att_dst, h, a_src, a_dst);
    k_goff<<<(N_GRAPHS + 1 + B - 1) / B, B, 0, stream>>>(batch, go);
    k_place2<<<2048, B, 0, stream>>>(part_, pcur, cursor, bucket);
    int waves_per_block = B / 64;
    int gather_blocks = (N_NODES + waves_per_block - 1) / waves_per_block;
    k_gather<<<gather_blocks, B, 0, stream>>>(cursor, bucket, h, a_src, a_dst, bias,
                                              W_gate, b_gate, oacc, ge);
    k_pool_out<<<N_GRAPHS, B, 0, stream>>>(oacc, ge, go, W_out, b_out, out);
}

// Round 7
// 269.537 us; speedup vs baseline: 1.0914x; 1.0914x over previous
//
#include <hip/hip_runtime.h>
#include <hip/hip_fp16.h>
#include <math.h>

#define N_NODES 50000
#define N_EDGES 1600000
#define N_GRAPHS 512
#define HID 32
#define NEG_SLOPE 0.2f
#define SM_EPS 1e-16f
#define PAD 80          // max in-degree slots; dst~Poisson(32), P(deg>=80)*N ~ 5e-7
#define NBIN 64         // radix bins over dst
#define BIN_W 782       // ceil-ish: bins 0..62 = 782 nodes, bin 63 = 734
#define BIN_CAP 27000   // 25000 mean + ~12 sigma
#define NWAVE 5000      // 1250 blocks x 4 waves
#define EPW 320         // edges per wave (5 chunks of 64)

// ---------------- kernel 1: edge records + per-wave 64-bin counts (ballot, no atomics) ----------------
__global__ __launch_bounds__(256) void k_rec_count(const int* __restrict__ ei,
                                                   const float* __restrict__ ea,
                                                   const float* __restrict__ W_edge,
                                                   const float* __restrict__ att_edge,
                                                   uint2* __restrict__ rec,
                                                   int* __restrict__ wcnt) {
    __shared__ float sv[3];
    if (threadIdx.x < 3) {
        float v = 0.f;
        for (int j = 0; j < 32; ++j) v += W_edge[threadIdx.x * 32 + j] * att_edge[j];
        sv[threadIdx.x] = v;
    }
    __syncthreads();
    int lane = threadIdx.x & 63;
    int w = blockIdx.x * 4 + (threadIdx.x >> 6);
    int ebase = w * EPW;
    int cnt = 0;                       // count for bin == lane
    for (int it = 0; it < 5; ++it) {
        int e = ebase + it * 64 + lane;
        int s = ei[e];
        int d = ei[N_EDGES + e];
        float aev = ea[e * 3 + 0] * sv[0] + ea[e * 3 + 1] * sv[1] + ea[e * 3 + 2] * sv[2];
        rec[e] = make_uint2((unsigned)d | ((unsigned)s << 16), __float_as_uint(aev));
        int bin = d / BIN_W;
        for (int bb = 0; bb < NBIN; ++bb) {
            unsigned long long m = __ballot(bin == bb);
            if (lane == bb) cnt += __popcll(m);
        }
    }
    wcnt[w * NBIN + lane] = cnt;
}

// ---------------- kernel 2: per-bin exclusive scan over 5000 wave counts ----------------
__global__ __launch_bounds__(256) void k_scan(const int* __restrict__ wcnt,
                                              int* __restrict__ wbase,
                                              int* __restrict__ stotal) {
    int b = blockIdx.x;   // bin
    int t = threadIdx.x;
    __shared__ int sp[256];
    int local[20];
    int sum = 0;
#pragma unroll
    for (int i = 0; i < 20; ++i) {
        int w = t * 20 + i;
        int v = (w < NWAVE) ? wcnt[w * NBIN + b] : 0;
        local[i] = sum;
        sum += v;
    }
    sp[t] = sum;
    __syncthreads();
    for (int ofs = 1; ofs < 256; ofs <<= 1) {
        int v = (t >= ofs) ? sp[t - ofs] : 0;
        __syncthreads();
        sp[t] += v;
        __syncthreads();
    }
    int base = (t == 0) ? 0 : sp[t - 1];
    int tot = sp[255];
#pragma unroll
    for (int i = 0; i < 20; ++i) {
        int w = t * 20 + i;
        if (w < NWAVE) wbase[w * NBIN + b] = b * BIN_CAP + base + local[i];
    }
    if (t == 0) stotal[b] = tot < BIN_CAP ? tot : BIN_CAP;
}

// ---------------- kernel 3: ballot-ranked scatter into 64 partitions (deterministic) ----------------
__global__ __launch_bounds__(256) void k_part2(const uint2* __restrict__ rec,
                                               const int* __restrict__ wbase,
                                               uint2* __restrict__ part) {
    int lane = threadIdx.x & 63;
    int w = blockIdx.x * 4 + (threadIdx.x >> 6);
    int bl = wbase[w * NBIN + lane];   // running base for bin == lane
    int ebase = w * EPW;
    unsigned long long below = (lane == 63) ? 0x7FFFFFFFFFFFFFFFull : ((1ull << lane) - 1);
    for (int it = 0; it < 5; ++it) {
        int e = ebase + it * 64 + lane;
        uint2 r = rec[e];
        int bin = (int)(r.x & 0xFFFF) / BIN_W;
        for (int bb = 0; bb < NBIN; ++bb) {
            unsigned long long m = __ballot(bin == bb);
            int bs = __shfl(bl, bb);
            if (bin == bb) {
                int pos = bs + __popcll(m & below);
                if (pos < (bb + 1) * BIN_CAP) part[pos] = r;
            }
            if (lane == bb) bl += __popcll(m);
        }
    }
}

// ---------------- kernel 4: LDS bucket-row assembly, dense coalesced writeback ----------------
__global__ __launch_bounds__(256) void k_asm(const uint2* __restrict__ part,
                                             const int* __restrict__ stotal,
                                             unsigned* __restrict__ bucket,
                                             int* __restrict__ cursor) {
    int b = blockIdx.x >> 2;   // bin
    int q = blockIdx.x & 3;    // quarter of the bin
    int lo = b * BIN_W + q * 196;
    int bhi = (b + 1) * BIN_W; if (bhi > N_NODES) bhi = N_NODES;
    int hi = lo + 196; if (hi > bhi) hi = bhi;
    int nrow = hi - lo;
    __shared__ int lcur[196];
    __shared__ unsigned lbuck[196 * PAD];   // 62.7 KB
    int t = threadIdx.x;
    for (int i = t; i < 196; i += 256) lcur[i] = 0;
    __syncthreads();
    int cnt = stotal[b];
    const uint2* p = part + (size_t)b * BIN_CAP;
    for (int i = t; i < cnt; i += 256) {
        uint2 r = p[i];
        int li = (int)(r.x & 0xFFFF) - lo;
        if ((unsigned)li < (unsigned)nrow) {
            unsigned s = r.x >> 16;
            unsigned short hb = __half_as_ushort(__float2half_rn(__uint_as_float(r.y)));
            int pos = atomicAdd(&lcur[li], 1);
            if (pos < PAD) lbuck[li * PAD + pos] = s | ((unsigned)hb << 16);
        }
    }
    __syncthreads();
    // dense coalesced writeback: rows [lo,hi) are contiguous in LDS and global
    int tot4 = nrow * PAD / 4;
    uint4* gb = (uint4*)(bucket + (size_t)lo * PAD);
    const uint4* lb = (const uint4*)lbuck;
    for (int i = t; i < tot4; i += 256) gb[i] = lb[i];
    for (int i = t; i < nrow; i += 256) cursor[lo + i] = lcur[i];
}

// ---------------- kernel 5: node transform h = x@W, a_src, a_dst ----------------
__global__ void k_node(const float* __restrict__ x, const float* __restrict__ W,
                       const float* __restrict__ att_src, const float* __restrict__ att_dst,
                       float* __restrict__ h, float* __restrict__ a_src, float* __restrict__ a_dst) {
    __shared__ float sW[12 * 32];
    __shared__ float sas[32], sad[32];
    int t = threadIdx.x;
    for (int i = t; i < 12 * 32; i += blockDim.x) sW[i] = W[i];
    if (t < 32) { sas[t] = att_src[t]; sad[t] = att_dst[t]; }
    __syncthreads();
    int n = blockIdx.x * blockDim.x + t;
    if (n >= N_NODES) return;

    float xv[12];
#pragma unroll
    for (int j = 0; j < 12; ++j) xv[j] = x[n * 12 + j];

    float as = 0.f, ad = 0.f;
#pragma unroll
    for (int k = 0; k < 32; ++k) {
        float acc = 0.f;
#pragma unroll
        for (int j = 0; j < 12; ++j) acc += xv[j] * sW[j * 32 + k];
        h[(size_t)n * 32 + k] = acc;
        as += acc * sas[k];
        ad += acc * sad[k];
    }
    a_src[n] = as;
    a_dst[n] = ad;
}

// ---------------- kernel 6: graph boundary offsets (batch is sorted) ----------------
__global__ void k_goff(const int* __restrict__ batch, int* __restrict__ go) {
    int g = blockIdx.x * blockDim.x + threadIdx.x;
    if (g > N_GRAPHS) return;
    if (g == N_GRAPHS) { go[g] = N_NODES; return; }
    int lo = 0, hi = N_NODES;
    while (lo < hi) {
        int mid = (lo + hi) >> 1;
        if (batch[mid] < g) lo = mid + 1; else hi = mid;
    }
    go[g] = lo;
}

// ---------------- kernel 7: wave-per-node gather; lane = (es 0..15, cg 0..3 x 8ch) ----------------
__global__ __launch_bounds__(256) void k_gather(const int* __restrict__ cursor,
                                                const unsigned* __restrict__ bucket,
                                                const float* __restrict__ h,
                                                const float* __restrict__ a_src,
                                                const float* __restrict__ a_dst,
                                                const float* __restrict__ bias,
                                                const float* __restrict__ W_gate,
                                                const float* __restrict__ b_gate,
                                                float* __restrict__ oacc,
                                                float* __restrict__ ge) {
    int n = blockIdx.x * (blockDim.x >> 6) + (threadIdx.x >> 6);
    if (n >= N_NODES) return;
    int l = threadIdx.x & 63;
    int es = l >> 2;        // edge subgroup 0..15
    int cg = l & 3;         // channel group 0..3 (8 floats)

    int deg_full = cursor[n];
    int degc = deg_full < PAD ? deg_full : PAD;
    float adst_n = a_dst[n];
    const unsigned* row = bucket + (size_t)n * PAD;

    float c0 = 0.f, c1 = 0.f, c2 = 0.f, c3 = 0.f, c4 = 0.f, c5 = 0.f, c6 = 0.f, c7 = 0.f;
    float wsum = 0.f, aevsum = 0.f;
    int j = es;
    for (; j + 16 < degc; j += 32) {
        unsigned p0 = row[j], p1 = row[j + 16];
        int s0 = p0 & 0xFFFF, s1 = p1 & 0xFFFF;
        float aev0 = __half2float(__ushort_as_half((unsigned short)(p0 >> 16)));
        float aev1 = __half2float(__ushort_as_half((unsigned short)(p1 >> 16)));
        float as0 = a_src[s0], as1 = a_src[s1];
        const float4 ha0 = *(const float4*)(h + (size_t)s0 * 32 + cg * 8);
        const float4 hb0 = *(const float4*)(h + (size_t)s0 * 32 + cg * 8 + 4);
        const float4 ha1 = *(const float4*)(h + (size_t)s1 * 32 + cg * 8);
        const float4 hb1 = *(const float4*)(h + (size_t)s1 * 32 + cg * 8 + 4);
        float a0 = as0 + adst_n + aev0; a0 = a0 > 0.f ? a0 : NEG_SLOPE * a0;
        float a1 = as1 + adst_n + aev1; a1 = a1 > 0.f ? a1 : NEG_SLOPE * a1;
        float w0 = __expf(a0), w1 = __expf(a1);
        wsum += w0 + w1; aevsum += aev0 + aev1;
        c0 += w0 * ha0.x + w1 * ha1.x;  c1 += w0 * ha0.y + w1 * ha1.y;
        c2 += w0 * ha0.z + w1 * ha1.z;  c3 += w0 * ha0.w + w1 * ha1.w;
        c4 += w0 * hb0.x + w1 * hb1.x;  c5 += w0 * hb0.y + w1 * hb1.y;
        c6 += w0 * hb0.z + w1 * hb1.z;  c7 += w0 * hb0.w + w1 * hb1.w;
    }
    if (j < degc) {
        unsigned p0 = row[j];
        int s0 = p0 & 0xFFFF;
        float aev0 = __half2float(__ushort_as_half((unsigned short)(p0 >> 16)));
        float a0 = a_src[s0] + adst_n + aev0; a0 = a0 > 0.f ? a0 : NEG_SLOPE * a0;
        float w0 = __expf(a0);
        const float4 ha0 = *(const float4*)(h + (size_t)s0 * 32 + cg * 8);
        const float4 hb0 = *(const float4*)(h + (size_t)s0 * 32 + cg * 8 + 4);
        wsum += w0; aevsum += aev0;
        c0 += w0 * ha0.x; c1 += w0 * ha0.y; c2 += w0 * ha0.z; c3 += w0 * ha0.w;
        c4 += w0 * hb0.x; c5 += w0 * hb0.y; c6 += w0 * hb0.z; c7 += w0 * hb0.w;
    }

#pragma unroll
    for (int m = 4; m <= 32; m <<= 1) {
        c0 += __shfl_xor(c0, m); c1 += __shfl_xor(c1, m);
        c2 += __shfl_xor(c2, m); c3 += __shfl_xor(c3, m);
        c4 += __shfl_xor(c4, m); c5 += __shfl_xor(c5, m);
        c6 += __shfl_xor(c6, m); c7 += __shfl_xor(c7, m);
        wsum += __shfl_xor(wsum, m); aevsum += __shfl_xor(aevsum, m);
    }

    float dgm = deg_full > 1 ? (float)deg_full : 1.f;
    float al = a_src[n] + adst_n + aevsum / dgm;
    al = al > 0.f ? al : NEG_SLOPE * al;
    float el = __expf(al);
    float zi = 1.f / (wsum + el + SM_EPS);

    if (es == 0) {
        const float4 hna = *(const float4*)(h + (size_t)n * 32 + cg * 8);
        const float4 hnb = *(const float4*)(h + (size_t)n * 32 + cg * 8 + 4);
        const float4 bva = *(const float4*)(bias + cg * 8);
        const float4 bvb = *(const float4*)(bias + cg * 8 + 4);
        float4 va, vb;
        va.x = (c0 + el * hna.x) * zi + bva.x;
        va.y = (c1 + el * hna.y) * zi + bva.y;
        va.z = (c2 + el * hna.z) * zi + bva.z;
        va.w = (c3 + el * hna.w) * zi + bva.w;
        vb.x = (c4 + el * hnb.x) * zi + bvb.x;
        vb.y = (c5 + el * hnb.y) * zi + bvb.y;
        vb.z = (c6 + el * hnb.z) * zi + bvb.z;
        vb.w = (c7 + el * hnb.w) * zi + bvb.w;
        va.x = va.x > 0.f ? va.x : 0.f;  va.y = va.y > 0.f ? va.y : 0.f;
        va.z = va.z > 0.f ? va.z : 0.f;  va.w = va.w > 0.f ? va.w : 0.f;
        vb.x = vb.x > 0.f ? vb.x : 0.f;  vb.y = vb.y > 0.f ? vb.y : 0.f;
        vb.z = vb.z > 0.f ? vb.z : 0.f;  vb.w = vb.w > 0.f ? vb.w : 0.f;
        *(float4*)(oacc + (size_t)n * 32 + cg * 8) = va;
        *(float4*)(oacc + (size_t)n * 32 + cg * 8 + 4) = vb;
        const float4 wga = *(const float4*)(W_gate + cg * 8);
        const float4 wgb = *(const float4*)(W_gate + cg * 8 + 4);
        float g = va.x * wga.x + va.y * wga.y + va.z * wga.z + va.w * wga.w
                + vb.x * wgb.x + vb.y * wgb.y + vb.z * wgb.z + vb.w * wgb.w;
        g += __shfl_xor(g, 1);
        g += __shfl_xor(g, 2);
        if (cg == 0) {
            g += b_gate[0];
            ge[n] = __expf(g);
        }
    }
}

// ---------------- kernel 8: per-graph pooling + output head ----------------
__global__ __launch_bounds__(256) void k_pool_out(const float* __restrict__ oacc,
                                                  const float* __restrict__ ge,
                                                  const int* __restrict__ go,
                                                  const float* __restrict__ W_out,
                                                  const float* __restrict__ b_out,
                                                  float* __restrict__ out) {
    int g = blockIdx.x;
    int beg = go[g], end = go[g + 1];
    int t = threadIdx.x;
    __shared__ float swz[4];
    __shared__ float part[8][32];
    __shared__ float sgz;

    float s = 0.f;
    for (int n = beg + t; n < end; n += 256) s += ge[n];
#pragma unroll
    for (int ofs = 32; ofs > 0; ofs >>= 1) s += __shfl_down(s, ofs);
    if ((t & 63) == 0) swz[t >> 6] = s;
    __syncthreads();
    if (t == 0) sgz = swz[0] + swz[1] + swz[2] + swz[3];
    __syncthreads();
    float gz = sgz;

    int c = t & 31, ng = t >> 5;
    float acc = 0.f;
    for (int n = beg + ng; n < end; n += 8)
        acc += oacc[(size_t)n * 32 + c] * ge[n];
    part[ng][c] = acc;
    __syncthreads();
    if (t < 32) {
        float p = 0.f;
#pragma unroll
        for (int i = 0; i < 8; ++i) p += part[i][t];
        p /= (gz + SM_EPS);
        float o = p * W_out[t];
#pragma unroll
        for (int ofs = 16; ofs > 0; ofs >>= 1) o += __shfl_down(o, ofs);
        if (t == 0) out[g] = 1.f / (1.f + __expf(-(o + b_out[0])));
    }
}

extern "C" void kernel_launch(void* const* d_in, const int* in_sizes, int n_in,
                              void* d_out, int out_size, void* d_ws, size_t ws_size,
                              hipStream_t stream) {
    const float* x        = (const float*)d_in[0];
    const int*   ei       = (const int*)  d_in[1];
    const float* ea       = (const float*)d_in[2];
    const int*   batch    = (const int*)  d_in[3];
    const float* W        = (const float*)d_in[4];
    const float* att_src  = (const float*)d_in[5];
    const float* att_dst  = (const float*)d_in[6];
    const float* W_edge   = (const float*)d_in[7];
    const float* att_edge = (const float*)d_in[8];
    const float* bias     = (const float*)d_in[9];
    const float* W_gate   = (const float*)d_in[10];
    const float* b_gate   = (const float*)d_in[11];
    const float* W_out    = (const float*)d_in[12];
    const float* b_out    = (const float*)d_in[13];
    float* out = (float*)d_out;

    // workspace layout (rec dead after k_part2; oacc overlaps rec, born in k_gather)
    char* wsb = (char*)d_ws;
    uint2*    rec    = (uint2*)wsb;                              // E uint2 = 12.8 MB
    float*    oacc   = (float*)wsb;                              // 32N floats = 6.4 MB (union)
    char*     p1     = wsb + (size_t)N_EDGES * sizeof(uint2);
    uint2*    part_  = (uint2*)p1;                               // NBIN*BIN_CAP uint2 = 13.8 MB
    float*    h      = (float*)(part_ + (size_t)NBIN * BIN_CAP); // 32N
    unsigned* bucket = (unsigned*)(h + (size_t)32 * N_NODES);    // N*PAD uint = 16 MB
    float*    a_src  = (float*)(bucket + (size_t)N_NODES * PAD); // N
    float*    a_dst  = a_src + N_NODES;                          // N
    float*    ge     = a_dst + N_NODES;                          // N
    int*      go     = (int*)(ge + N_NODES);                     // G+1
    int*      cursor = go + N_GRAPHS + 1;                        // N (fully written by k_asm)
    int*      wcnt   = cursor + N_NODES;                         // NWAVE*NBIN = 1.28 MB
    int*      wbase  = wcnt + NWAVE * NBIN;                      // NWAVE*NBIN
    int*      stotal = wbase + NWAVE * NBIN;                     // NBIN

    const int B = 256;
    k_rec_count<<<1250, B, 0, stream>>>(ei, ea, W_edge, att_edge, rec, wcnt);
    k_scan<<<NBIN, B, 0, stream>>>(wcnt, wbase, stotal);
    k_part2<<<1250, B, 0, stream>>>(rec, wbase, part_);
    k_asm<<<NBIN * 4, B, 0, stream>>>(part_, stotal, bucket, cursor);
    k_node<<<(N_NODES + B - 1) / B, B, 0, stream>>>(x, W, att_src, att_dst, h, a_src, a_dst);
    k_goff<<<(N_GRAPHS + 1 + B - 1) / B, B, 0, stream>>>(batch, go);
    int gather_blocks = (N_NODES + 3) / 4;
    k_gather<<<gather_blocks, B, 0, stream>>>(cursor, bucket, h, a_src, a_dst, bias,
                                              W_gate, b_gate, oacc, ge);
    k_pool_out<<<N_GRAPHS, B, 0, stream>>>(oacc, ge, go, W_out, b_out, out);
}

// Round 8
// 201.327 us; speedup vs baseline: 1.4611x; 1.3388x over previous
//
#include <hip/hip_runtime.h>
#include <hip/hip_fp16.h>
#include <math.h>

#define N_NODES 50000
#define N_EDGES 1600000
#define N_GRAPHS 512
#define HID 32
#define NEG_SLOPE 0.2f
#define SM_EPS 1e-16f
#define PAD 80          // max in-degree slots; dst~Poisson(32), P(deg>=80)*N ~ 5e-7
#define NBIN 64         // radix bins over dst
#define BIN_W 782       // bins 0..62 = 782 nodes, bin 63 = 734
#define BIN_CAP 27000   // 25000 mean + ~12 sigma
#define NWAVE 5000      // 1250 blocks x 4 waves
#define EPW 320         // edges per wave (5 chunks of 64)

// ---------------- kernel 1: edge records + per-wave 64-bin LDS histogram ----------------
__global__ __launch_bounds__(256) void k_rec_count(const int* __restrict__ ei,
                                                   const float* __restrict__ ea,
                                                   const float* __restrict__ W_edge,
                                                   const float* __restrict__ att_edge,
                                                   uint2* __restrict__ rec,
                                                   int* __restrict__ wcnt) {
    __shared__ float sv[3];
    __shared__ int lh[4][NBIN];
    int t = threadIdx.x;
    if (t < 3) {
        float v = 0.f;
        for (int j = 0; j < 32; ++j) v += W_edge[t * 32 + j] * att_edge[j];
        sv[t] = v;
    }
    lh[t >> 6][t & 63] = 0;
    __syncthreads();
    int lane = t & 63;
    int wl = t >> 6;
    int w = blockIdx.x * 4 + wl;
    int ebase = w * EPW;
#pragma unroll
    for (int it = 0; it < 5; ++it) {
        int e = ebase + it * 64 + lane;
        int s = ei[e];
        int d = ei[N_EDGES + e];
        float aev = ea[e * 3 + 0] * sv[0] + ea[e * 3 + 1] * sv[1] + ea[e * 3 + 2] * sv[2];
        rec[e] = make_uint2((unsigned)d | ((unsigned)s << 16), __float_as_uint(aev));
        atomicAdd(&lh[wl][d / BIN_W], 1);
    }
    __syncthreads();
    wcnt[w * NBIN + lane] = lh[wl][lane];
}

// ---------------- kernel 2: per-bin exclusive scan over 5000 wave counts ----------------
__global__ __launch_bounds__(256) void k_scan(const int* __restrict__ wcnt,
                                              int* __restrict__ wbase,
                                              int* __restrict__ stotal) {
    int b = blockIdx.x;   // bin
    int t = threadIdx.x;
    __shared__ int sp[256];
    int local[20];
    int sum = 0;
#pragma unroll
    for (int i = 0; i < 20; ++i) {
        int w = t * 20 + i;
        int v = (w < NWAVE) ? wcnt[w * NBIN + b] : 0;
        local[i] = sum;
        sum += v;
    }
    sp[t] = sum;
    __syncthreads();
    for (int ofs = 1; ofs < 256; ofs <<= 1) {
        int v = (t >= ofs) ? sp[t - ofs] : 0;
        __syncthreads();
        sp[t] += v;
        __syncthreads();
    }
    int base = (t == 0) ? 0 : sp[t - 1];
    int tot = sp[255];
#pragma unroll
    for (int i = 0; i < 20; ++i) {
        int w = t * 20 + i;
        if (w < NWAVE) wbase[w * NBIN + b] = b * BIN_CAP + base + local[i];
    }
    if (t == 0) stotal[b] = tot < BIN_CAP ? tot : BIN_CAP;
}

// ---------------- kernel 3: LDS-cursor ranked scatter into 64 partitions ----------------
__global__ __launch_bounds__(256) void k_part2(const uint2* __restrict__ rec,
                                               const int* __restrict__ wbase,
                                               uint2* __restrict__ part) {
    __shared__ int lb[4][NBIN];
    int t = threadIdx.x;
    int lane = t & 63, wl = t >> 6;
    int w = blockIdx.x * 4 + wl;
    lb[wl][lane] = wbase[w * NBIN + lane];   // running cursor, seeded per wave
    __syncthreads();
    int ebase = w * EPW;
#pragma unroll
    for (int it = 0; it < 5; ++it) {
        int e = ebase + it * 64 + lane;
        uint2 r = rec[e];
        int bin = (int)(r.x & 0xFFFF) / BIN_W;
        int pos = atomicAdd(&lb[wl][bin], 1);
        if (pos < (bin + 1) * BIN_CAP) part[pos] = r;
    }
}

// ---------------- kernel 4: LDS bucket-row assembly, 1024 threads (16 waves) ----------------
__global__ __launch_bounds__(1024) void k_asm(const uint2* __restrict__ part,
                                              const int* __restrict__ stotal,
                                              unsigned* __restrict__ bucket,
                                              int* __restrict__ cursor) {
    int b = blockIdx.x >> 2;   // bin
    int q = blockIdx.x & 3;    // quarter of the bin
    int lo = b * BIN_W + q * 196;
    int bhi = (b + 1) * BIN_W; if (bhi > N_NODES) bhi = N_NODES;
    int hi = lo + 196; if (hi > bhi) hi = bhi;
    int nrow = hi - lo;
    __shared__ int lcur[196];
    __shared__ unsigned lbuck[196 * PAD];   // 62.7 KB
    int t = threadIdx.x;
    if (t < 196) lcur[t] = 0;
    __syncthreads();
    int cnt = stotal[b];
    const uint2* p = part + (size_t)b * BIN_CAP;
    for (int i = t; i < cnt; i += 1024) {
        uint2 r = p[i];
        int li = (int)(r.x & 0xFFFF) - lo;
        if ((unsigned)li < (unsigned)nrow) {
            unsigned s = r.x >> 16;
            unsigned short hb = __half_as_ushort(__float2half_rn(__uint_as_float(r.y)));
            int pos = atomicAdd(&lcur[li], 1);
            if (pos < PAD) lbuck[li * PAD + pos] = s | ((unsigned)hb << 16);
        }
    }
    __syncthreads();
    // dense coalesced writeback
    int tot4 = nrow * PAD / 4;
    uint4* gb = (uint4*)(bucket + (size_t)lo * PAD);
    const uint4* lb = (const uint4*)lbuck;
    for (int i = t; i < tot4; i += 1024) gb[i] = lb[i];
    if (t < nrow) cursor[lo + t] = lcur[t];
}

// ---------------- kernel 5: node transform h = x@W, a_src, a_dst ----------------
__global__ void k_node(const float* __restrict__ x, const float* __restrict__ W,
                       const float* __restrict__ att_src, const float* __restrict__ att_dst,
                       float* __restrict__ h, float* __restrict__ a_src, float* __restrict__ a_dst) {
    __shared__ float sW[12 * 32];
    __shared__ float sas[32], sad[32];
    int t = threadIdx.x;
    for (int i = t; i < 12 * 32; i += blockDim.x) sW[i] = W[i];
    if (t < 32) { sas[t] = att_src[t]; sad[t] = att_dst[t]; }
    __syncthreads();
    int n = blockIdx.x * blockDim.x + t;
    if (n >= N_NODES) return;

    float xv[12];
#pragma unroll
    for (int j = 0; j < 12; ++j) xv[j] = x[n * 12 + j];

    float as = 0.f, ad = 0.f;
#pragma unroll
    for (int k = 0; k < 32; ++k) {
        float acc = 0.f;
#pragma unroll
        for (int j = 0; j < 12; ++j) acc += xv[j] * sW[j * 32 + k];
        h[(size_t)n * 32 + k] = acc;
        as += acc * sas[k];
        ad += acc * sad[k];
    }
    a_src[n] = as;
    a_dst[n] = ad;
}

// ---------------- kernel 6: graph boundary offsets (batch is sorted) ----------------
__global__ void k_goff(const int* __restrict__ batch, int* __restrict__ go) {
    int g = blockIdx.x * blockDim.x + threadIdx.x;
    if (g > N_GRAPHS) return;
    if (g == N_GRAPHS) { go[g] = N_NODES; return; }
    int lo = 0, hi = N_NODES;
    while (lo < hi) {
        int mid = (lo + hi) >> 1;
        if (batch[mid] < g) lo = mid + 1; else hi = mid;
    }
    go[g] = lo;
}

// ---------------- kernel 7: wave-per-node gather; lane = (es 0..15, cg 0..3 x 8ch) ----------------
__global__ __launch_bounds__(256) void k_gather(const int* __restrict__ cursor,
                                                const unsigned* __restrict__ bucket,
                                                const float* __restrict__ h,
                                                const float* __restrict__ a_src,
                                                const float* __restrict__ a_dst,
                                                const float* __restrict__ bias,
                                                const float* __restrict__ W_gate,
                                                const float* __restrict__ b_gate,
                                                float* __restrict__ oacc,
                                                float* __restrict__ ge) {
    int n = blockIdx.x * (blockDim.x >> 6) + (threadIdx.x >> 6);
    if (n >= N_NODES) return;
    int l = threadIdx.x & 63;
    int es = l >> 2;        // edge subgroup 0..15
    int cg = l & 3;         // channel group 0..3 (8 floats)

    int deg_full = cursor[n];
    int degc = deg_full < PAD ? deg_full : PAD;
    float adst_n = a_dst[n];
    const unsigned* row = bucket + (size_t)n * PAD;

    float c0 = 0.f, c1 = 0.f, c2 = 0.f, c3 = 0.f, c4 = 0.f, c5 = 0.f, c6 = 0.f, c7 = 0.f;
    float wsum = 0.f, aevsum = 0.f;
    int j = es;
    for (; j + 16 < degc; j += 32) {
        unsigned p0 = row[j], p1 = row[j + 16];
        int s0 = p0 & 0xFFFF, s1 = p1 & 0xFFFF;
        float aev0 = __half2float(__ushort_as_half((unsigned short)(p0 >> 16)));
        float aev1 = __half2float(__ushort_as_half((unsigned short)(p1 >> 16)));
        float as0 = a_src[s0], as1 = a_src[s1];
        const float4 ha0 = *(const float4*)(h + (size_t)s0 * 32 + cg * 8);
        const float4 hb0 = *(const float4*)(h + (size_t)s0 * 32 + cg * 8 + 4);
        const float4 ha1 = *(const float4*)(h + (size_t)s1 * 32 + cg * 8);
        const float4 hb1 = *(const float4*)(h + (size_t)s1 * 32 + cg * 8 + 4);
        float a0 = as0 + adst_n + aev0; a0 = a0 > 0.f ? a0 : NEG_SLOPE * a0;
        float a1 = as1 + adst_n + aev1; a1 = a1 > 0.f ? a1 : NEG_SLOPE * a1;
        float w0 = __expf(a0), w1 = __expf(a1);
        wsum += w0 + w1; aevsum += aev0 + aev1;
        c0 += w0 * ha0.x + w1 * ha1.x;  c1 += w0 * ha0.y + w1 * ha1.y;
        c2 += w0 * ha0.z + w1 * ha1.z;  c3 += w0 * ha0.w + w1 * ha1.w;
        c4 += w0 * hb0.x + w1 * hb1.x;  c5 += w0 * hb0.y + w1 * hb1.y;
        c6 += w0 * hb0.z + w1 * hb1.z;  c7 += w0 * hb0.w + w1 * hb1.w;
    }
    if (j < degc) {
        unsigned p0 = row[j];
        int s0 = p0 & 0xFFFF;
        float aev0 = __half2float(__ushort_as_half((unsigned short)(p0 >> 16)));
        float a0 = a_src[s0] + adst_n + aev0; a0 = a0 > 0.f ? a0 : NEG_SLOPE * a0;
        float w0 = __expf(a0);
        const float4 ha0 = *(const float4*)(h + (size_t)s0 * 32 + cg * 8);
        const float4 hb0 = *(const float4*)(h + (size_t)s0 * 32 + cg * 8 + 4);
        wsum += w0; aevsum += aev0;
        c0 += w0 * ha0.x; c1 += w0 * ha0.y; c2 += w0 * ha0.z; c3 += w0 * ha0.w;
        c4 += w0 * hb0.x; c5 += w0 * hb0.y; c6 += w0 * hb0.z; c7 += w0 * hb0.w;
    }

#pragma unroll
    for (int m = 4; m <= 32; m <<= 1) {
        c0 += __shfl_xor(c0, m); c1 += __shfl_xor(c1, m);
        c2 += __shfl_xor(c2, m); c3 += __shfl_xor(c3, m);
        c4 += __shfl_xor(c4, m); c5 += __shfl_xor(c5, m);
        c6 += __shfl_xor(c6, m); c7 += __shfl_xor(c7, m);
        wsum += __shfl_xor(wsum, m); aevsum += __shfl_xor(aevsum, m);
    }

    float dgm = deg_full > 1 ? (float)deg_full : 1.f;
    float al = a_src[n] + adst_n + aevsum / dgm;
    al = al > 0.f ? al : NEG_SLOPE * al;
    float el = __expf(al);
    float zi = 1.f / (wsum + el + SM_EPS);

    if (es == 0) {
        const float4 hna = *(const float4*)(h + (size_t)n * 32 + cg * 8);
        const float4 hnb = *(const float4*)(h + (size_t)n * 32 + cg * 8 + 4);
        const float4 bva = *(const float4*)(bias + cg * 8);
        const float4 bvb = *(const float4*)(bias + cg * 8 + 4);
        float4 va, vb;
        va.x = (c0 + el * hna.x) * zi + bva.x;
        va.y = (c1 + el * hna.y) * zi + bva.y;
        va.z = (c2 + el * hna.z) * zi + bva.z;
        va.w = (c3 + el * hna.w) * zi + bva.w;
        vb.x = (c4 + el * hnb.x) * zi + bvb.x;
        vb.y = (c5 + el * hnb.y) * zi + bvb.y;
        vb.z = (c6 + el * hnb.z) * zi + bvb.z;
        vb.w = (c7 + el * hnb.w) * zi + bvb.w;
        va.x = va.x > 0.f ? va.x : 0.f;  va.y = va.y > 0.f ? va.y : 0.f;
        va.z = va.z > 0.f ? va.z : 0.f;  va.w = va.w > 0.f ? va.w : 0.f;
        vb.x = vb.x > 0.f ? vb.x : 0.f;  vb.y = vb.y > 0.f ? vb.y : 0.f;
        vb.z = vb.z > 0.f ? vb.z : 0.f;  vb.w = vb.w > 0.f ? vb.w : 0.f;
        *(float4*)(oacc + (size_t)n * 32 + cg * 8) = va;
        *(float4*)(oacc + (size_t)n * 32 + cg * 8 + 4) = vb;
        const float4 wga = *(const float4*)(W_gate + cg * 8);
        const float4 wgb = *(const float4*)(W_gate + cg * 8 + 4);
        float g = va.x * wga.x + va.y * wga.y + va.z * wga.z + va.w * wga.w
                + vb.x * wgb.x + vb.y * wgb.y + vb.z * wgb.z + vb.w * wgb.w;
        g += __shfl_xor(g, 1);
        g += __shfl_xor(g, 2);
        if (cg == 0) {
            g += b_gate[0];
            ge[n] = __expf(g);
        }
    }
}

// ---------------- kernel 8: per-graph pooling + output head ----------------
__global__ __launch_bounds__(256) void k_pool_out(const float* __restrict__ oacc,
                                                  const float* __restrict__ ge,
                                                  const int* __restrict__ go,
                                                  const float* __restrict__ W_out,
                                                  const float* __restrict__ b_out,
                                                  float* __restrict__ out) {
    int g = blockIdx.x;
    int beg = go[g], end = go[g + 1];
    int t = threadIdx.x;
    __shared__ float swz[4];
    __shared__ float part[8][32];
    __shared__ float sgz;

    float s = 0.f;
    for (int n = beg + t; n < end; n += 256) s += ge[n];
#pragma unroll
    for (int ofs = 32; ofs > 0; ofs >>= 1) s += __shfl_down(s, ofs);
    if ((t & 63) == 0) swz[t >> 6] = s;
    __syncthreads();
    if (t == 0) sgz = swz[0] + swz[1] + swz[2] + swz[3];
    __syncthreads();
    float gz = sgz;

    int c = t & 31, ng = t >> 5;
    float acc = 0.f;
    for (int n = beg + ng; n < end; n += 8)
        acc += oacc[(size_t)n * 32 + c] * ge[n];
    part[ng][c] = acc;
    __syncthreads();
    if (t < 32) {
        float p = 0.f;
#pragma unroll
        for (int i = 0; i < 8; ++i) p += part[i][t];
        p /= (gz + SM_EPS);
        float o = p * W_out[t];
#pragma unroll
        for (int ofs = 16; ofs > 0; ofs >>= 1) o += __shfl_down(o, ofs);
        if (t == 0) out[g] = 1.f / (1.f + __expf(-(o + b_out[0])));
    }
}

extern "C" void kernel_launch(void* const* d_in, const int* in_sizes, int n_in,
                              void* d_out, int out_size, void* d_ws, size_t ws_size,
                              hipStream_t stream) {
    const float* x        = (const float*)d_in[0];
    const int*   ei       = (const int*)  d_in[1];
    const float* ea       = (const float*)d_in[2];
    const int*   batch    = (const int*)  d_in[3];
    const float* W        = (const float*)d_in[4];
    const float* att_src  = (const float*)d_in[5];
    const float* att_dst  = (const float*)d_in[6];
    const float* W_edge   = (const float*)d_in[7];
    const float* att_edge = (const float*)d_in[8];
    const float* bias     = (const float*)d_in[9];
    const float* W_gate   = (const float*)d_in[10];
    const float* b_gate   = (const float*)d_in[11];
    const float* W_out    = (const float*)d_in[12];
    const float* b_out    = (const float*)d_in[13];
    float* out = (float*)d_out;

    // workspace layout (rec dead after k_part2; oacc overlaps rec, born in k_gather)
    char* wsb = (char*)d_ws;
    uint2*    rec    = (uint2*)wsb;                              // E uint2 = 12.8 MB
    float*    oacc   = (float*)wsb;                              // 32N floats = 6.4 MB (union)
    char*     p1     = wsb + (size_t)N_EDGES * sizeof(uint2);
    uint2*    part_  = (uint2*)p1;                               // NBIN*BIN_CAP uint2 = 13.8 MB
    float*    h      = (float*)(part_ + (size_t)NBIN * BIN_CAP); // 32N
    unsigned* bucket = (unsigned*)(h + (size_t)32 * N_NODES);    // N*PAD uint = 16 MB
    float*    a_src  = (float*)(bucket + (size_t)N_NODES * PAD); // N
    float*    a_dst  = a_src + N_NODES;                          // N
    float*    ge     = a_dst + N_NODES;                          // N
    int*      go     = (int*)(ge + N_NODES);                     // G+1
    int*      cursor = go + N_GRAPHS + 1;                        // N (fully written by k_asm)
    int*      wcnt   = cursor + N_NODES;                         // NWAVE*NBIN
    int*      wbase  = wcnt + NWAVE * NBIN;                      // NWAVE*NBIN
    int*      stotal = wbase + NWAVE * NBIN;                     // NBIN

    const int B = 256;
    k_rec_count<<<1250, B, 0, stream>>>(ei, ea, W_edge, att_edge, rec, wcnt);
    k_scan<<<NBIN, B, 0, stream>>>(wcnt, wbase, stotal);
    k_part2<<<1250, B, 0, stream>>>(rec, wbase, part_);
    k_asm<<<NBIN * 4, 1024, 0, stream>>>(part_, stotal, bucket, cursor);
    k_node<<<(N_NODES + B - 1) / B, B, 0, stream>>>(x, W, att_src, att_dst, h, a_src, a_dst);
    k_goff<<<(N_GRAPHS + 1 + B - 1) / B, B, 0, stream>>>(batch, go);
    int gather_blocks = (N_NODES + 3) / 4;
    k_gather<<<gather_blocks, B, 0, stream>>>(cursor, bucket, h, a_src, a_dst, bias,
                                              W_gate, b_gate, oacc, ge);
    k_pool_out<<<N_GRAPHS, B, 0, stream>>>(oacc, ge, go, W_out, b_out, out);
}

// Round 9
// 193.153 us; speedup vs baseline: 1.5230x; 1.0423x over previous
//
#include <hip/hip_runtime.h>
#include <hip/hip_fp16.h>
#include <math.h>

#define N_NODES 50000
#define N_EDGES 1600000
#define N_GRAPHS 512
#define HID 32
#define NEG_SLOPE 0.2f
#define SM_EPS 1e-16f
#define PAD 80          // max in-degree slots; dst~Poisson(32), P(deg>=80)*N ~ 5e-7
#define NBIN 64         // radix bins over dst
#define BIN_W 782       // bins 0..62 = 782 nodes, bin 63 = 734
#define BIN_CAP 27000   // 25000 mean + ~12 sigma
#define NWAVE 5000      // 1250 blocks x 4 waves
#define EPW 320         // edges per wave (5 chunks of 64)

// ---------------- kernel 1: edge records + per-wave 64-bin LDS histogram ----------------
__global__ __launch_bounds__(256) void k_rec_count(const int* __restrict__ ei,
                                                   const float* __restrict__ ea,
                                                   const float* __restrict__ W_edge,
                                                   const float* __restrict__ att_edge,
                                                   uint2* __restrict__ rec,
                                                   int* __restrict__ wcnt) {
    __shared__ float sv[3];
    __shared__ int lh[4][NBIN];
    int t = threadIdx.x;
    if (t < 3) {
        float v = 0.f;
        for (int j = 0; j < 32; ++j) v += W_edge[t * 32 + j] * att_edge[j];
        sv[t] = v;
    }
    lh[t >> 6][t & 63] = 0;
    __syncthreads();
    int lane = t & 63;
    int wl = t >> 6;
    int w = blockIdx.x * 4 + wl;
    int ebase = w * EPW;
#pragma unroll
    for (int it = 0; it < 5; ++it) {
        int e = ebase + it * 64 + lane;
        int s = ei[e];
        int d = ei[N_EDGES + e];
        float aev = ea[e * 3 + 0] * sv[0] + ea[e * 3 + 1] * sv[1] + ea[e * 3 + 2] * sv[2];
        rec[e] = make_uint2((unsigned)d | ((unsigned)s << 16), __float_as_uint(aev));
        atomicAdd(&lh[wl][d / BIN_W], 1);
    }
    __syncthreads();
    wcnt[w * NBIN + lane] = lh[wl][lane];
}

// ---------------- kernel 2: per-bin exclusive scan over 5000 wave counts ----------------
__global__ __launch_bounds__(256) void k_scan(const int* __restrict__ wcnt,
                                              int* __restrict__ wbase,
                                              int* __restrict__ stotal) {
    int b = blockIdx.x;   // bin
    int t = threadIdx.x;
    __shared__ int sp[256];
    int local[20];
    int sum = 0;
#pragma unroll
    for (int i = 0; i < 20; ++i) {
        int w = t * 20 + i;
        int v = (w < NWAVE) ? wcnt[w * NBIN + b] : 0;
        local[i] = sum;
        sum += v;
    }
    sp[t] = sum;
    __syncthreads();
    for (int ofs = 1; ofs < 256; ofs <<= 1) {
        int v = (t >= ofs) ? sp[t - ofs] : 0;
        __syncthreads();
        sp[t] += v;
        __syncthreads();
    }
    int base = (t == 0) ? 0 : sp[t - 1];
    int tot = sp[255];
#pragma unroll
    for (int i = 0; i < 20; ++i) {
        int w = t * 20 + i;
        if (w < NWAVE) wbase[w * NBIN + b] = b * BIN_CAP + base + local[i];
    }
    if (t == 0) stotal[b] = tot < BIN_CAP ? tot : BIN_CAP;
}

// ---------------- kernel 3: LDS-cursor ranked scatter into 64 partitions ----------------
__global__ __launch_bounds__(256) void k_part2(const uint2* __restrict__ rec,
                                               const int* __restrict__ wbase,
                                               uint2* __restrict__ part) {
    __shared__ int lb[4][NBIN];
    int t = threadIdx.x;
    int lane = t & 63, wl = t >> 6;
    int w = blockIdx.x * 4 + wl;
    lb[wl][lane] = wbase[w * NBIN + lane];   // running cursor, seeded per wave
    __syncthreads();
    int ebase = w * EPW;
#pragma unroll
    for (int it = 0; it < 5; ++it) {
        int e = ebase + it * 64 + lane;
        uint2 r = rec[e];
        int bin = (int)(r.x & 0xFFFF) / BIN_W;
        int pos = atomicAdd(&lb[wl][bin], 1);
        if (pos < (bin + 1) * BIN_CAP) part[pos] = r;
    }
}

// ---------------- kernel 4: LDS bucket-row assembly, 1024 threads (16 waves) ----------------
__global__ __launch_bounds__(1024) void k_asm(const uint2* __restrict__ part,
                                              const int* __restrict__ stotal,
                                              unsigned* __restrict__ bucket,
                                              int* __restrict__ cursor) {
    int b = blockIdx.x >> 2;   // bin
    int q = blockIdx.x & 3;    // quarter of the bin
    int lo = b * BIN_W + q * 196;
    int bhi = (b + 1) * BIN_W; if (bhi > N_NODES) bhi = N_NODES;
    int hi = lo + 196; if (hi > bhi) hi = bhi;
    int nrow = hi - lo;
    __shared__ int lcur[196];
    __shared__ unsigned lbuck[196 * PAD];   // 62.7 KB
    int t = threadIdx.x;
    if (t < 196) lcur[t] = 0;
    __syncthreads();
    int cnt = stotal[b];
    const uint2* p = part + (size_t)b * BIN_CAP;
    for (int i = t; i < cnt; i += 1024) {
        uint2 r = p[i];
        int li = (int)(r.x & 0xFFFF) - lo;
        if ((unsigned)li < (unsigned)nrow) {
            unsigned s = r.x >> 16;
            unsigned short hb = __half_as_ushort(__float2half_rn(__uint_as_float(r.y)));
            int pos = atomicAdd(&lcur[li], 1);
            if (pos < PAD) lbuck[li * PAD + pos] = s | ((unsigned)hb << 16);
        }
    }
    __syncthreads();
    // dense coalesced writeback
    int tot4 = nrow * PAD / 4;
    uint4* gb = (uint4*)(bucket + (size_t)lo * PAD);
    const uint4* lb = (const uint4*)lbuck;
    for (int i = t; i < tot4; i += 1024) gb[i] = lb[i];
    if (t < nrow) cursor[lo + t] = lcur[t];
}

// ---------------- kernel 5: node transform h = x@W (fp16 out), a_src, a_dst ----------------
__global__ void k_node(const float* __restrict__ x, const float* __restrict__ W,
                       const float* __restrict__ att_src, const float* __restrict__ att_dst,
                       __half2* __restrict__ h2, float* __restrict__ a_src,
                       float* __restrict__ a_dst) {
    __shared__ float sW[12 * 32];
    __shared__ float sas[32], sad[32];
    int t = threadIdx.x;
    for (int i = t; i < 12 * 32; i += blockDim.x) sW[i] = W[i];
    if (t < 32) { sas[t] = att_src[t]; sad[t] = att_dst[t]; }
    __syncthreads();
    int n = blockIdx.x * blockDim.x + t;
    if (n >= N_NODES) return;

    float xv[12];
#pragma unroll
    for (int j = 0; j < 12; ++j) xv[j] = x[n * 12 + j];

    float hv[32];
    float as = 0.f, ad = 0.f;
#pragma unroll
    for (int k = 0; k < 32; ++k) {
        float acc = 0.f;
#pragma unroll
        for (int j = 0; j < 12; ++j) acc += xv[j] * sW[j * 32 + k];
        hv[k] = acc;
        as += acc * sas[k];
        ad += acc * sad[k];
    }
    a_src[n] = as;
    a_dst[n] = ad;

    __half2 hp[16];
#pragma unroll
    for (int k = 0; k < 16; ++k) hp[k] = __floats2half2_rn(hv[2 * k], hv[2 * k + 1]);
    uint4* dst = (uint4*)(h2 + (size_t)n * 16);
    const uint4* srcp = (const uint4*)hp;
#pragma unroll
    for (int k = 0; k < 4; ++k) dst[k] = srcp[k];
}

// ---------------- kernel 6: wave-per-node gather; lane = (es 0..15, cg 0..3 x 8ch) ----------------
__global__ __launch_bounds__(256) void k_gather(const int* __restrict__ cursor,
                                                const unsigned* __restrict__ bucket,
                                                const __half2* __restrict__ h2,
                                                const float* __restrict__ a_src,
                                                const float* __restrict__ a_dst,
                                                const float* __restrict__ bias,
                                                const float* __restrict__ W_gate,
                                                const float* __restrict__ b_gate,
                                                float* __restrict__ oacc,
                                                float* __restrict__ ge) {
    int n = blockIdx.x * (blockDim.x >> 6) + (threadIdx.x >> 6);
    if (n >= N_NODES) return;
    int l = threadIdx.x & 63;
    int es = l >> 2;        // edge subgroup 0..15
    int cg = l & 3;         // channel group 0..3 (8 halves = one dwordx4)

    int deg_full = cursor[n];
    int degc = deg_full < PAD ? deg_full : PAD;
    float adst_n = a_dst[n];
    const unsigned* row = bucket + (size_t)n * PAD;

    float c0 = 0.f, c1 = 0.f, c2 = 0.f, c3 = 0.f, c4 = 0.f, c5 = 0.f, c6 = 0.f, c7 = 0.f;
    float wsum = 0.f, aevsum = 0.f;
    int j = es;
    for (; j + 16 < degc; j += 32) {
        unsigned p0 = row[j], p1 = row[j + 16];
        int s0 = p0 & 0xFFFF, s1 = p1 & 0xFFFF;
        float aev0 = __half2float(__ushort_as_half((unsigned short)(p0 >> 16)));
        float aev1 = __half2float(__ushort_as_half((unsigned short)(p1 >> 16)));
        float as0 = a_src[s0], as1 = a_src[s1];
        const uint4 u0 = *(const uint4*)(h2 + (size_t)s0 * 16 + cg * 4);
        const uint4 u1 = *(const uint4*)(h2 + (size_t)s1 * 16 + cg * 4);
        float a0 = as0 + adst_n + aev0; a0 = a0 > 0.f ? a0 : NEG_SLOPE * a0;
        float a1 = as1 + adst_n + aev1; a1 = a1 > 0.f ? a1 : NEG_SLOPE * a1;
        float w0 = __expf(a0), w1 = __expf(a1);
        wsum += w0 + w1; aevsum += aev0 + aev1;
        float2 f;
        f = __half22float2(*(const __half2*)&u0.x); c0 += w0 * f.x; c1 += w0 * f.y;
        f = __half22float2(*(const __half2*)&u0.y); c2 += w0 * f.x; c3 += w0 * f.y;
        f = __half22float2(*(const __half2*)&u0.z); c4 += w0 * f.x; c5 += w0 * f.y;
        f = __half22float2(*(const __half2*)&u0.w); c6 += w0 * f.x; c7 += w0 * f.y;
        f = __half22float2(*(const __half2*)&u1.x); c0 += w1 * f.x; c1 += w1 * f.y;
        f = __half22float2(*(const __half2*)&u1.y); c2 += w1 * f.x; c3 += w1 * f.y;
        f = __half22float2(*(const __half2*)&u1.z); c4 += w1 * f.x; c5 += w1 * f.y;
        f = __half22float2(*(const __half2*)&u1.w); c6 += w1 * f.x; c7 += w1 * f.y;
    }
    if (j < degc) {
        unsigned p0 = row[j];
        int s0 = p0 & 0xFFFF;
        float aev0 = __half2float(__ushort_as_half((unsigned short)(p0 >> 16)));
        float a0 = a_src[s0] + adst_n + aev0; a0 = a0 > 0.f ? a0 : NEG_SLOPE * a0;
        float w0 = __expf(a0);
        const uint4 u0 = *(const uint4*)(h2 + (size_t)s0 * 16 + cg * 4);
        wsum += w0; aevsum += aev0;
        float2 f;
        f = __half22float2(*(const __half2*)&u0.x); c0 += w0 * f.x; c1 += w0 * f.y;
        f = __half22float2(*(const __half2*)&u0.y); c2 += w0 * f.x; c3 += w0 * f.y;
        f = __half22float2(*(const __half2*)&u0.z); c4 += w0 * f.x; c5 += w0 * f.y;
        f = __half22float2(*(const __half2*)&u0.w); c6 += w0 * f.x; c7 += w0 * f.y;
    }

#pragma unroll
    for (int m = 4; m <= 32; m <<= 1) {
        c0 += __shfl_xor(c0, m); c1 += __shfl_xor(c1, m);
        c2 += __shfl_xor(c2, m); c3 += __shfl_xor(c3, m);
        c4 += __shfl_xor(c4, m); c5 += __shfl_xor(c5, m);
        c6 += __shfl_xor(c6, m); c7 += __shfl_xor(c7, m);
        wsum += __shfl_xor(wsum, m); aevsum += __shfl_xor(aevsum, m);
    }

    float dgm = deg_full > 1 ? (float)deg_full : 1.f;
    float al = a_src[n] + adst_n + aevsum / dgm;
    al = al > 0.f ? al : NEG_SLOPE * al;
    float el = __expf(al);
    float zi = 1.f / (wsum + el + SM_EPS);

    if (es == 0) {          // lanes 0..3, 8 channels each
        const uint4 un = *(const uint4*)(h2 + (size_t)n * 16 + cg * 4);
        float hn[8];
        float2 f;
        f = __half22float2(*(const __half2*)&un.x); hn[0] = f.x; hn[1] = f.y;
        f = __half22float2(*(const __half2*)&un.y); hn[2] = f.x; hn[3] = f.y;
        f = __half22float2(*(const __half2*)&un.z); hn[4] = f.x; hn[5] = f.y;
        f = __half22float2(*(const __half2*)&un.w); hn[6] = f.x; hn[7] = f.y;
        const float4 bva = *(const float4*)(bias + cg * 8);
        const float4 bvb = *(const float4*)(bias + cg * 8 + 4);
        float4 va, vb;
        va.x = (c0 + el * hn[0]) * zi + bva.x;
        va.y = (c1 + el * hn[1]) * zi + bva.y;
        va.z = (c2 + el * hn[2]) * zi + bva.z;
        va.w = (c3 + el * hn[3]) * zi + bva.w;
        vb.x = (c4 + el * hn[4]) * zi + bvb.x;
        vb.y = (c5 + el * hn[5]) * zi + bvb.y;
        vb.z = (c6 + el * hn[6]) * zi + bvb.z;
        vb.w = (c7 + el * hn[7]) * zi + bvb.w;
        va.x = va.x > 0.f ? va.x : 0.f;  va.y = va.y > 0.f ? va.y : 0.f;
        va.z = va.z > 0.f ? va.z : 0.f;  va.w = va.w > 0.f ? va.w : 0.f;
        vb.x = vb.x > 0.f ? vb.x : 0.f;  vb.y = vb.y > 0.f ? vb.y : 0.f;
        vb.z = vb.z > 0.f ? vb.z : 0.f;  vb.w = vb.w > 0.f ? vb.w : 0.f;
        *(float4*)(oacc + (size_t)n * 32 + cg * 8) = va;
        *(float4*)(oacc + (size_t)n * 32 + cg * 8 + 4) = vb;
        const float4 wga = *(const float4*)(W_gate + cg * 8);
        const float4 wgb = *(const float4*)(W_gate + cg * 8 + 4);
        float g = va.x * wga.x + va.y * wga.y + va.z * wga.z + va.w * wga.w
                + vb.x * wgb.x + vb.y * wgb.y + vb.z * wgb.z + vb.w * wgb.w;
        g += __shfl_xor(g, 1);
        g += __shfl_xor(g, 2);
        if (cg == 0) {
            g += b_gate[0];
            ge[n] = __expf(g);
        }
    }
}

// ---------------- kernel 7: per-graph pooling + output head (inline boundary search) ----------------
__global__ __launch_bounds__(256) void k_pool_out(const float* __restrict__ oacc,
                                                  const float* __restrict__ ge,
                                                  const int* __restrict__ batch,
                                                  const float* __restrict__ W_out,
                                                  const float* __restrict__ b_out,
                                                  float* __restrict__ out) {
    int g = blockIdx.x;
    int t = threadIdx.x;
    __shared__ int sbound[2];
    if (t < 2) {
        int target = g + t;   // t==0: beg(g), t==1: beg(g+1)
        int lo = 0, hi = N_NODES;
        if (target >= N_GRAPHS) lo = N_NODES;
        else {
            while (lo < hi) {
                int mid = (lo + hi) >> 1;
                if (batch[mid] < target) lo = mid + 1; else hi = mid;
            }
        }
        sbound[t] = lo;
    }
    __syncthreads();
    int beg = sbound[0], end = sbound[1];
    __shared__ float swz[4];
    __shared__ float part[8][32];
    __shared__ float sgz;

    float s = 0.f;
    for (int n = beg + t; n < end; n += 256) s += ge[n];
#pragma unroll
    for (int ofs = 32; ofs > 0; ofs >>= 1) s += __shfl_down(s, ofs);
    if ((t & 63) == 0) swz[t >> 6] = s;
    __syncthreads();
    if (t == 0) sgz = swz[0] + swz[1] + swz[2] + swz[3];
    __syncthreads();
    float gz = sgz;

    int c = t & 31, ng = t >> 5;
    float acc = 0.f;
    for (int n = beg + ng; n < end; n += 8)
        acc += oacc[(size_t)n * 32 + c] * ge[n];
    part[ng][c] = acc;
    __syncthreads();
    if (t < 32) {
        float p = 0.f;
#pragma unroll
        for (int i = 0; i < 8; ++i) p += part[i][t];
        p /= (gz + SM_EPS);
        float o = p * W_out[t];
#pragma unroll
        for (int ofs = 16; ofs > 0; ofs >>= 1) o += __shfl_down(o, ofs);
        if (t == 0) out[g] = 1.f / (1.f + __expf(-(o + b_out[0])));
    }
}

extern "C" void kernel_launch(void* const* d_in, const int* in_sizes, int n_in,
                              void* d_out, int out_size, void* d_ws, size_t ws_size,
                              hipStream_t stream) {
    const float* x        = (const float*)d_in[0];
    const int*   ei       = (const int*)  d_in[1];
    const float* ea       = (const float*)d_in[2];
    const int*   batch    = (const int*)  d_in[3];
    const float* W        = (const float*)d_in[4];
    const float* att_src  = (const float*)d_in[5];
    const float* att_dst  = (const float*)d_in[6];
    const float* W_edge   = (const float*)d_in[7];
    const float* att_edge = (const float*)d_in[8];
    const float* bias     = (const float*)d_in[9];
    const float* W_gate   = (const float*)d_in[10];
    const float* b_gate   = (const float*)d_in[11];
    const float* W_out    = (const float*)d_in[12];
    const float* b_out    = (const float*)d_in[13];
    float* out = (float*)d_out;

    // workspace layout (rec dead after k_part2; oacc overlaps rec, born in k_gather)
    char* wsb = (char*)d_ws;
    uint2*    rec    = (uint2*)wsb;                              // E uint2 = 12.8 MB
    float*    oacc   = (float*)wsb;                              // 32N floats = 6.4 MB (union)
    char*     p1     = wsb + (size_t)N_EDGES * sizeof(uint2);
    uint2*    part_  = (uint2*)p1;                               // NBIN*BIN_CAP uint2 = 13.8 MB
    __half2*  h2     = (__half2*)(part_ + (size_t)NBIN * BIN_CAP); // 16N half2 = 3.2 MB
    unsigned* bucket = (unsigned*)(h2 + (size_t)16 * N_NODES);   // N*PAD uint = 16 MB
    float*    a_src  = (float*)(bucket + (size_t)N_NODES * PAD); // N
    float*    a_dst  = a_src + N_NODES;                          // N
    float*    ge     = a_dst + N_NODES;                          // N
    int*      cursor = (int*)(ge + N_NODES);                     // N (fully written by k_asm)
    int*      wcnt   = cursor + N_NODES;                         // NWAVE*NBIN
    int*      wbase  = wcnt + NWAVE * NBIN;                      // NWAVE*NBIN
    int*      stotal = wbase + NWAVE * NBIN;                     // NBIN

    const int B = 256;
    k_rec_count<<<1250, B, 0, stream>>>(ei, ea, W_edge, att_edge, rec, wcnt);
    k_scan<<<NBIN, B, 0, stream>>>(wcnt, wbase, stotal);
    k_part2<<<1250, B, 0, stream>>>(rec, wbase, part_);
    k_asm<<<NBIN * 4, 1024, 0, stream>>>(part_, stotal, bucket, cursor);
    k_node<<<(N_NODES + B - 1) / B, B, 0, stream>>>(x, W, att_src, att_dst, h2, a_src, a_dst);
    int gather_blocks = (N_NODES + 3) / 4;
    k_gather<<<gather_blocks, B, 0, stream>>>(cursor, bucket, h2, a_src, a_dst, bias,
                                              W_gate, b_gate, oacc, ge);
    k_pool_out<<<N_GRAPHS, B, 0, stream>>>(oacc, ge, batch, W_out, b_out, out);
}

// Round 10
// 183.568 us; speedup vs baseline: 1.6025x; 1.0522x over previous
//
#include <hip/hip_runtime.h>
#include <hip/hip_fp16.h>
#include <math.h>

#define N_NODES 50000
#define N_EDGES 1600000
#define N_GRAPHS 512
#define HID 32
#define NEG_SLOPE 0.2f
#define SM_EPS 1e-16f
#define PAD 80          // max in-degree slots; dst~Poisson(32), P(deg>=80)*N ~ 5e-7
#define NBIN 64         // radix bins over dst
#define BIN_W 782       // bins 0..62 = 782 nodes, bin 63 = 734
#define BIN_CAP 27000   // 25000 mean + ~12 sigma
#define EPT 10          // edges per thread in k_part_direct
#define PART_BLOCKS 625 // 625 * 256 * 10 = 1,600,000 exactly

// ---------------- kernel 1: fused histogram + global-base + ranked scatter ----------------
// Block covers 2560 edges: LDS 64-bin histogram -> 1 global atomic per bin per block
// (40k atomics over 64 addresses) -> LDS-cursor ranked scatter. ~40 entries/bin/block
// = 320 B contiguous runs -> good L2 write merging. No rec array, no scan kernel.
__global__ __launch_bounds__(256) void k_part_direct(const int* __restrict__ ei,
                                                     const float* __restrict__ ea,
                                                     const float* __restrict__ W_edge,
                                                     const float* __restrict__ att_edge,
                                                     uint2* __restrict__ part,
                                                     int* __restrict__ pcur) {
    __shared__ float sv[3];
    __shared__ int lcnt[NBIN], lcur[NBIN];
    int t = threadIdx.x;
    if (t < 3) {
        float v = 0.f;
        for (int j = 0; j < 32; ++j) v += W_edge[t * 32 + j] * att_edge[j];
        sv[t] = v;
    }
    if (t < NBIN) lcnt[t] = 0;
    __syncthreads();

    uint2 r[EPT];
    int bin[EPT];
    int ebase = blockIdx.x * (256 * EPT) + t;
#pragma unroll
    for (int i = 0; i < EPT; ++i) {
        int e = ebase + i * 256;
        int s = ei[e];
        int d = ei[N_EDGES + e];
        float aev = ea[e * 3 + 0] * sv[0] + ea[e * 3 + 1] * sv[1] + ea[e * 3 + 2] * sv[2];
        r[i] = make_uint2((unsigned)d | ((unsigned)s << 16), __float_as_uint(aev));
        bin[i] = d / BIN_W;
        atomicAdd(&lcnt[bin[i]], 1);
    }
    __syncthreads();
    if (t < NBIN) lcur[t] = atomicAdd(pcur + t, lcnt[t]);
    __syncthreads();
#pragma unroll
    for (int i = 0; i < EPT; ++i) {
        int pos = atomicAdd(&lcur[bin[i]], 1);
        if (pos < BIN_CAP) part[(size_t)bin[i] * BIN_CAP + pos] = r[i];
    }
}

// ---------------- kernel 2: node transform h = x@W (fp16 out), a_src, a_dst ----------------
__global__ void k_node(const float* __restrict__ x, const float* __restrict__ W,
                       const float* __restrict__ att_src, const float* __restrict__ att_dst,
                       __half2* __restrict__ h2, float* __restrict__ a_src,
                       float* __restrict__ a_dst) {
    __shared__ float sW[12 * 32];
    __shared__ float sas[32], sad[32];
    int t = threadIdx.x;
    for (int i = t; i < 12 * 32; i += blockDim.x) sW[i] = W[i];
    if (t < 32) { sas[t] = att_src[t]; sad[t] = att_dst[t]; }
    __syncthreads();
    int n = blockIdx.x * blockDim.x + t;
    if (n >= N_NODES) return;

    float xv[12];
#pragma unroll
    for (int j = 0; j < 12; ++j) xv[j] = x[n * 12 + j];

    float hv[32];
    float as = 0.f, ad = 0.f;
#pragma unroll
    for (int k = 0; k < 32; ++k) {
        float acc = 0.f;
#pragma unroll
        for (int j = 0; j < 12; ++j) acc += xv[j] * sW[j * 32 + k];
        hv[k] = acc;
        as += acc * sas[k];
        ad += acc * sad[k];
    }
    a_src[n] = as;
    a_dst[n] = ad;

    __half2 hp[16];
#pragma unroll
    for (int k = 0; k < 16; ++k) hp[k] = __floats2half2_rn(hv[2 * k], hv[2 * k + 1]);
    uint4* dst = (uint4*)(h2 + (size_t)n * 16);
    const uint4* srcp = (const uint4*)hp;
#pragma unroll
    for (int k = 0; k < 4; ++k) dst[k] = srcp[k];
}

// ---------------- kernel 3: fused LDS row assembly + wave-per-node gather ----------------
// Block (bin b, quarter q): phase 1 filters bin partition into 196 LDS rows;
// phase 2: 16 waves process nodes from LDS rows (broadcast reads), gather h2 global.
__global__ __launch_bounds__(1024) void k_asm_gather(const uint2* __restrict__ part,
                                                     const int* __restrict__ pcur,
                                                     const __half2* __restrict__ h2,
                                                     const float* __restrict__ a_src,
                                                     const float* __restrict__ a_dst,
                                                     const float* __restrict__ bias,
                                                     const float* __restrict__ W_gate,
                                                     const float* __restrict__ b_gate,
                                                     float* __restrict__ oacc,
                                                     float* __restrict__ ge) {
    int b = blockIdx.x >> 2;   // bin
    int q = blockIdx.x & 3;    // quarter
    int lo = b * BIN_W + q * 196;
    int bhi = (b + 1) * BIN_W; if (bhi > N_NODES) bhi = N_NODES;
    int hi = lo + 196; if (hi > bhi) hi = bhi;
    int nrow = hi - lo;
    __shared__ int lcur[196];
    __shared__ unsigned lbuck[196 * PAD];   // 62.7 KB
    int t = threadIdx.x;
    if (t < 196) lcur[t] = 0;
    __syncthreads();

    // ---- phase 1: assemble rows in LDS ----
    int cnt = pcur[b]; if (cnt > BIN_CAP) cnt = BIN_CAP;
    const uint2* p = part + (size_t)b * BIN_CAP;
    for (int i = t; i < cnt; i += 1024) {
        uint2 r = p[i];
        int li = (int)(r.x & 0xFFFF) - lo;
        if ((unsigned)li < (unsigned)nrow) {
            unsigned s = r.x >> 16;
            unsigned short hb = __half_as_ushort(__float2half_rn(__uint_as_float(r.y)));
            int pos = atomicAdd(&lcur[li], 1);
            if (pos < PAD) lbuck[li * PAD + pos] = s | ((unsigned)hb << 16);
        }
    }
    __syncthreads();

    // ---- phase 2: wave-per-node gather from LDS rows ----
    int l = t & 63, wl = t >> 6;   // 16 waves
    int es = l >> 2;               // edge subgroup 0..15
    int cg = l & 3;                // channel group 0..3 (8 halves = one dwordx4)

    for (int li = wl; li < nrow; li += 16) {
        int n = lo + li;
        int deg_full = lcur[li];
        int degc = deg_full < PAD ? deg_full : PAD;
        float adst_n = a_dst[n];
        const unsigned* row = lbuck + li * PAD;

        float c0 = 0.f, c1 = 0.f, c2 = 0.f, c3 = 0.f, c4 = 0.f, c5 = 0.f, c6 = 0.f, c7 = 0.f;
        float wsum = 0.f, aevsum = 0.f;
        int j = es;
        for (; j + 16 < degc; j += 32) {
            unsigned p0 = row[j], p1 = row[j + 16];
            int s0 = p0 & 0xFFFF, s1 = p1 & 0xFFFF;
            float aev0 = __half2float(__ushort_as_half((unsigned short)(p0 >> 16)));
            float aev1 = __half2float(__ushort_as_half((unsigned short)(p1 >> 16)));
            float as0 = a_src[s0], as1 = a_src[s1];
            const uint4 u0 = *(const uint4*)(h2 + (size_t)s0 * 16 + cg * 4);
            const uint4 u1 = *(const uint4*)(h2 + (size_t)s1 * 16 + cg * 4);
            float a0 = as0 + adst_n + aev0; a0 = a0 > 0.f ? a0 : NEG_SLOPE * a0;
            float a1 = as1 + adst_n + aev1; a1 = a1 > 0.f ? a1 : NEG_SLOPE * a1;
            float w0 = __expf(a0), w1 = __expf(a1);
            wsum += w0 + w1; aevsum += aev0 + aev1;
            float2 f;
            f = __half22float2(*(const __half2*)&u0.x); c0 += w0 * f.x; c1 += w0 * f.y;
            f = __half22float2(*(const __half2*)&u0.y); c2 += w0 * f.x; c3 += w0 * f.y;
            f = __half22float2(*(const __half2*)&u0.z); c4 += w0 * f.x; c5 += w0 * f.y;
            f = __half22float2(*(const __half2*)&u0.w); c6 += w0 * f.x; c7 += w0 * f.y;
            f = __half22float2(*(const __half2*)&u1.x); c0 += w1 * f.x; c1 += w1 * f.y;
            f = __half22float2(*(const __half2*)&u1.y); c2 += w1 * f.x; c3 += w1 * f.y;
            f = __half22float2(*(const __half2*)&u1.z); c4 += w1 * f.x; c5 += w1 * f.y;
            f = __half22float2(*(const __half2*)&u1.w); c6 += w1 * f.x; c7 += w1 * f.y;
        }
        if (j < degc) {
            unsigned p0 = row[j];
            int s0 = p0 & 0xFFFF;
            float aev0 = __half2float(__ushort_as_half((unsigned short)(p0 >> 16)));
            float a0 = a_src[s0] + adst_n + aev0; a0 = a0 > 0.f ? a0 : NEG_SLOPE * a0;
            float w0 = __expf(a0);
            const uint4 u0 = *(const uint4*)(h2 + (size_t)s0 * 16 + cg * 4);
            wsum += w0; aevsum += aev0;
            float2 f;
            f = __half22float2(*(const __half2*)&u0.x); c0 += w0 * f.x; c1 += w0 * f.y;
            f = __half22float2(*(const __half2*)&u0.y); c2 += w0 * f.x; c3 += w0 * f.y;
            f = __half22float2(*(const __half2*)&u0.z); c4 += w0 * f.x; c5 += w0 * f.y;
            f = __half22float2(*(const __half2*)&u0.w); c6 += w0 * f.x; c7 += w0 * f.y;
        }

#pragma unroll
        for (int m = 4; m <= 32; m <<= 1) {
            c0 += __shfl_xor(c0, m); c1 += __shfl_xor(c1, m);
            c2 += __shfl_xor(c2, m); c3 += __shfl_xor(c3, m);
            c4 += __shfl_xor(c4, m); c5 += __shfl_xor(c5, m);
            c6 += __shfl_xor(c6, m); c7 += __shfl_xor(c7, m);
            wsum += __shfl_xor(wsum, m); aevsum += __shfl_xor(aevsum, m);
        }

        float dgm = deg_full > 1 ? (float)deg_full : 1.f;
        float al = a_src[n] + adst_n + aevsum / dgm;
        al = al > 0.f ? al : NEG_SLOPE * al;
        float el = __expf(al);
        float zi = 1.f / (wsum + el + SM_EPS);

        if (es == 0) {          // lanes 0..3, 8 channels each
            const uint4 un = *(const uint4*)(h2 + (size_t)n * 16 + cg * 4);
            float hn[8];
            float2 f;
            f = __half22float2(*(const __half2*)&un.x); hn[0] = f.x; hn[1] = f.y;
            f = __half22float2(*(const __half2*)&un.y); hn[2] = f.x; hn[3] = f.y;
            f = __half22float2(*(const __half2*)&un.z); hn[4] = f.x; hn[5] = f.y;
            f = __half22float2(*(const __half2*)&un.w); hn[6] = f.x; hn[7] = f.y;
            const float4 bva = *(const float4*)(bias + cg * 8);
            const float4 bvb = *(const float4*)(bias + cg * 8 + 4);
            float4 va, vb;
            va.x = (c0 + el * hn[0]) * zi + bva.x;
            va.y = (c1 + el * hn[1]) * zi + bva.y;
            va.z = (c2 + el * hn[2]) * zi + bva.z;
            va.w = (c3 + el * hn[3]) * zi + bva.w;
            vb.x = (c4 + el * hn[4]) * zi + bvb.x;
            vb.y = (c5 + el * hn[5]) * zi + bvb.y;
            vb.z = (c6 + el * hn[6]) * zi + bvb.z;
            vb.w = (c7 + el * hn[7]) * zi + bvb.w;
            va.x = va.x > 0.f ? va.x : 0.f;  va.y = va.y > 0.f ? va.y : 0.f;
            va.z = va.z > 0.f ? va.z : 0.f;  va.w = va.w > 0.f ? va.w : 0.f;
            vb.x = vb.x > 0.f ? vb.x : 0.f;  vb.y = vb.y > 0.f ? vb.y : 0.f;
            vb.z = vb.z > 0.f ? vb.z : 0.f;  vb.w = vb.w > 0.f ? vb.w : 0.f;
            *(float4*)(oacc + (size_t)n * 32 + cg * 8) = va;
            *(float4*)(oacc + (size_t)n * 32 + cg * 8 + 4) = vb;
            const float4 wga = *(const float4*)(W_gate + cg * 8);
            const float4 wgb = *(const float4*)(W_gate + cg * 8 + 4);
            float g = va.x * wga.x + va.y * wga.y + va.z * wga.z + va.w * wga.w
                    + vb.x * wgb.x + vb.y * wgb.y + vb.z * wgb.z + vb.w * wgb.w;
            g += __shfl_xor(g, 1);
            g += __shfl_xor(g, 2);
            if (cg == 0) {
                g += b_gate[0];
                ge[n] = __expf(g);
            }
        }
    }
}

// ---------------- kernel 4: per-graph pooling + output head (inline boundary search) ----------------
__global__ __launch_bounds__(256) void k_pool_out(const float* __restrict__ oacc,
                                                  const float* __restrict__ ge,
                                                  const int* __restrict__ batch,
                                                  const float* __restrict__ W_out,
                                                  const float* __restrict__ b_out,
                                                  float* __restrict__ out) {
    int g = blockIdx.x;
    int t = threadIdx.x;
    __shared__ int sbound[2];
    if (t < 2) {
        int target = g + t;
        int lo = 0, hi = N_NODES;
        if (target >= N_GRAPHS) lo = N_NODES;
        else {
            while (lo < hi) {
                int mid = (lo + hi) >> 1;
                if (batch[mid] < target) lo = mid + 1; else hi = mid;
            }
        }
        sbound[t] = lo;
    }
    __syncthreads();
    int beg = sbound[0], end = sbound[1];
    __shared__ float swz[4];
    __shared__ float part[8][32];
    __shared__ float sgz;

    float s = 0.f;
    for (int n = beg + t; n < end; n += 256) s += ge[n];
#pragma unroll
    for (int ofs = 32; ofs > 0; ofs >>= 1) s += __shfl_down(s, ofs);
    if ((t & 63) == 0) swz[t >> 6] = s;
    __syncthreads();
    if (t == 0) sgz = swz[0] + swz[1] + swz[2] + swz[3];
    __syncthreads();
    float gz = sgz;

    int c = t & 31, ng = t >> 5;
    float acc = 0.f;
    for (int n = beg + ng; n < end; n += 8)
        acc += oacc[(size_t)n * 32 + c] * ge[n];
    part[ng][c] = acc;
    __syncthreads();
    if (t < 32) {
        float p = 0.f;
#pragma unroll
        for (int i = 0; i < 8; ++i) p += part[i][t];
        p /= (gz + SM_EPS);
        float o = p * W_out[t];
#pragma unroll
        for (int ofs = 16; ofs > 0; ofs >>= 1) o += __shfl_down(o, ofs);
        if (t == 0) out[g] = 1.f / (1.f + __expf(-(o + b_out[0])));
    }
}

extern "C" void kernel_launch(void* const* d_in, const int* in_sizes, int n_in,
                              void* d_out, int out_size, void* d_ws, size_t ws_size,
                              hipStream_t stream) {
    const float* x        = (const float*)d_in[0];
    const int*   ei       = (const int*)  d_in[1];
    const float* ea       = (const float*)d_in[2];
    const int*   batch    = (const int*)  d_in[3];
    const float* W        = (const float*)d_in[4];
    const float* att_src  = (const float*)d_in[5];
    const float* att_dst  = (const float*)d_in[6];
    const float* W_edge   = (const float*)d_in[7];
    const float* att_edge = (const float*)d_in[8];
    const float* bias     = (const float*)d_in[9];
    const float* W_gate   = (const float*)d_in[10];
    const float* b_gate   = (const float*)d_in[11];
    const float* W_out    = (const float*)d_in[12];
    const float* b_out    = (const float*)d_in[13];
    float* out = (float*)d_out;

    // workspace layout (no overlaps — ws is plentiful)
    char* wsb = (char*)d_ws;
    uint2*    part_  = (uint2*)wsb;                                // NBIN*BIN_CAP uint2 = 13.8 MB
    __half2*  h2     = (__half2*)(part_ + (size_t)NBIN * BIN_CAP); // 16N half2 = 3.2 MB
    float*    a_src  = (float*)(h2 + (size_t)16 * N_NODES);        // N
    float*    a_dst  = a_src + N_NODES;                            // N
    float*    ge     = a_dst + N_NODES;                            // N
    float*    oacc   = ge + N_NODES;                               // 32N
    int*      pcur   = (int*)(oacc + (size_t)32 * N_NODES);        // NBIN (zeroed)

    hipMemsetAsync(pcur, 0, NBIN * sizeof(int), stream);

    const int B = 256;
    k_part_direct<<<PART_BLOCKS, B, 0, stream>>>(ei, ea, W_edge, att_edge, part_, pcur);
    k_node<<<(N_NODES + B - 1) / B, B, 0, stream>>>(x, W, att_src, att_dst, h2, a_src, a_dst);
    k_asm_gather<<<NBIN * 4, 1024, 0, stream>>>(part_, pcur, h2, a_src, a_dst, bias,
                                                W_gate, b_gate, oacc, ge);
    k_pool_out<<<N_GRAPHS, B, 0, stream>>>(oacc, ge, batch, W_out, b_out, out);
}